// Round 1
// 1305.629 us; speedup vs baseline: 1.7871x; 1.7871x over previous
//
#include <hip/hip_runtime.h>

// NucleiGNN fused forward: B=2048 molecules, one block per molecule.
// Dense matmuls (q/k/v/Wo/Wf) now run on MFMA via split-bf16 (bf16x3):
//   x = hi + lo (two bf16), C ~= Ah*Bh + Al*Bh + Ah*Bl  (f32 accumulate)
// Weights are pre-split+packed into MFMA B-fragment order in d_ws by a
// prep kernel. hn/msg A-operands live in LDS as bf16 hi/lo tiles
// (row stride 136 -> 4-bank row step, <=2-way conflicts). LN stats are
// computed with register shuffles (32 lanes share a row). Attention,
// softmax, tanh stay f32 VALU, identical to the previous version.

#define NBATCH 2048
#define NATOM  64
#define NF     128
#define NLAYER 3
#define STR    132   // f32 row stride for 64x128 LDS tiles
#define ASTR   65    // attention row stride
#define ASTRB  136   // bf16 A-tile row stride (272B rows: 16B aligned, 4-bank step)
#define NTH    512

using bf16x8 = __attribute__((ext_vector_type(8))) __bf16;
using f32x4  = __attribute__((ext_vector_type(4))) float;

__device__ __forceinline__ float bf2f(unsigned short u) {
    union { unsigned int i; float f; } v; v.i = ((unsigned int)u) << 16; return v.f;
}
__device__ __forceinline__ unsigned short f2bf(float f) {
    union { float ff; unsigned int i; } v; v.ff = f;
    unsigned int x = v.i;
    if ((x & 0x7f800000u) == 0x7f800000u) return (unsigned short)(x >> 16);
    return (unsigned short)((x + 0x7fffu + ((x >> 16) & 1u)) >> 16);
}

template<bool BF16>
__device__ __forceinline__ float ldT(const void* p, int i) {
    if constexpr (BF16) return bf2f(((const unsigned short*)p)[i]);
    else                return ((const float*)p)[i];
}
template<bool BF16>
__device__ __forceinline__ float4 ld4T(const void* p, int i) {
    if constexpr (BF16) {
        ushort4 v = *(const ushort4*)((const unsigned short*)p + i);
        return make_float4(bf2f(v.x), bf2f(v.y), bf2f(v.z), bf2f(v.w));
    } else {
        return *(const float4*)((const float*)p + i);
    }
}

__device__ __forceinline__ void split4(float4 v, ushort4& hi, ushort4& lo) {
    hi.x = f2bf(v.x); lo.x = f2bf(v.x - bf2f(hi.x));
    hi.y = f2bf(v.y); lo.y = f2bf(v.y - bf2f(hi.y));
    hi.z = f2bf(v.z); lo.z = f2bf(v.z - bf2f(hi.z));
    hi.w = f2bf(v.w); lo.w = f2bf(v.w - bf2f(hi.w));
}

// LN row statistics from register tile h[4][4]; the 32 threads sharing a row
// are consecutive lanes (fq = lane&31), so 5 shfl_xor rounds reduce a row.
__device__ __forceinline__ void ln_stats(const float (&h)[4][4], float (&mu)[4], float (&rs)[4]) {
    #pragma unroll
    for (int i = 0; i < 4; ++i) {
        float s  = h[i][0] + h[i][1] + h[i][2] + h[i][3];
        float s2 = h[i][0]*h[i][0] + h[i][1]*h[i][1] + h[i][2]*h[i][2] + h[i][3]*h[i][3];
        #pragma unroll
        for (int m = 1; m <= 16; m <<= 1) {
            s  += __shfl_xor(s,  m, 64);
            s2 += __shfl_xor(s2, m, 64);
        }
        float mm = s * (1.f / 128.f);
        float vv = s2 * (1.f / 128.f) - mm * mm;
        mu[i] = mm;
        rs[i] = rsqrtf(fmaxf(vv, 0.f) + 1e-5f);
    }
}

// normalize h with (mu,rs), split to bf16 hi/lo, store into A tiles
__device__ __forceinline__ void write_a(const float (&h)[4][4], const float (&mu)[4], const float (&rs)[4],
                                        unsigned short* __restrict__ a_hi, unsigned short* __restrict__ a_lo,
                                        int r0, int fq) {
    #pragma unroll
    for (int i = 0; i < 4; ++i) {
        float4 x = make_float4((h[i][0]-mu[i])*rs[i], (h[i][1]-mu[i])*rs[i],
                               (h[i][2]-mu[i])*rs[i], (h[i][3]-mu[i])*rs[i]);
        ushort4 uh, ul;
        split4(x, uh, ul);
        *(ushort4*)&a_hi[(r0 + i) * ASTRB + fq * 4] = uh;
        *(ushort4*)&a_lo[(r0 + i) * ASTRB + fq * 4] = ul;
    }
}

// [64,128] A (bf16 hi/lo in LDS) @ [128,128] B (pre-packed bf16 hi/lo fragments
// in global) -> f32 dst tile (stride STR). 8 waves: wave w owns C rows
// (w&3)*16..+15, col tiles (w>>2)*4 .. +3. mfma_f32_16x16x32_bf16:
//   A: row = lane&15, k = 8*(lane>>4)+e ; B: col = lane&15, k = 8*(lane>>4)+e
//   C: col = lane&15, row = (lane>>4)*4 + reg        (m89-verified layout)
__device__ __forceinline__ void mfma_mm(const unsigned short* __restrict__ a_hi,
                                        const unsigned short* __restrict__ a_lo,
                                        const unsigned short* __restrict__ bp,
                                        float* __restrict__ dst, int lane, int wave)
{
    const int tr   = wave & 3;
    const int tjb  = (wave >> 2) << 2;   // 0 or 4
    const int abase = (tr * 16 + (lane & 15)) * ASTRB + ((lane >> 4) << 3);
    const unsigned short* bl = bp + 16384;
    f32x4 acc[4] = {{0.f,0.f,0.f,0.f},{0.f,0.f,0.f,0.f},{0.f,0.f,0.f,0.f},{0.f,0.f,0.f,0.f}};
    #pragma unroll
    for (int kc = 0; kc < 4; ++kc) {
        bf16x8 av_h = *(const bf16x8*)&a_hi[abase + kc * 32];
        bf16x8 av_l = *(const bf16x8*)&a_lo[abase + kc * 32];
        #pragma unroll
        for (int j = 0; j < 4; ++j) {
            const int bi = ((((kc << 3) + tjb + j) << 6) + lane) << 3;
            bf16x8 bv_h = *(const bf16x8*)&bp[bi];
            bf16x8 bv_l = *(const bf16x8*)&bl[bi];
            acc[j] = __builtin_amdgcn_mfma_f32_16x16x32_bf16(av_h, bv_h, acc[j], 0, 0, 0);
            acc[j] = __builtin_amdgcn_mfma_f32_16x16x32_bf16(av_l, bv_h, acc[j], 0, 0, 0);
            acc[j] = __builtin_amdgcn_mfma_f32_16x16x32_bf16(av_h, bv_l, acc[j], 0, 0, 0);
        }
    }
    const int crow = tr * 16 + ((lane >> 4) << 2);
    const int ccol = (tjb << 4) + (lane & 15);
    #pragma unroll
    for (int j = 0; j < 4; ++j) {
        #pragma unroll
        for (int r = 0; r < 4; ++r)
            dst[(crow + r) * STR + ccol + (j << 4)] = acc[j][r];
    }
}

// Pre-split weights into bf16 hi/lo, packed in MFMA B-fragment order.
// Slot layout: wpack[(kind*3 + l)*32768]: [0,16384)=hi frags, [16384,32768)=lo.
// Fragment index f = ((kc*8 + tj)*64 + lane)*8 + e <->
//   W[l][kc*32 + (lane>>4)*8 + e][tj*16 + (lane&15)]
template<bool BF16>
__global__ __launch_bounds__(256)
void prep_w(const void* __restrict__ Wq, const void* __restrict__ Wk,
            const void* __restrict__ Wv, const void* __restrict__ Wo,
            const void* __restrict__ Wf, unsigned short* __restrict__ wpack)
{
    {
        const unsigned int* w = (const unsigned int*)Wq;
        bool isbf = true;
        #pragma unroll
        for (int i = 0; i < 16; ++i) {
            unsigned int e = (w[i] >> 7) & 0xFFu;
            isbf = isbf && (e >= 0x60u && e <= 0x7Eu);
        }
        if (isbf != BF16) return;
    }
    const int mat  = blockIdx.x;            // 0..14 = kind*3 + l
    const int kind = mat / 3, l = mat % 3;
    const void* src = (kind == 0) ? Wq : (kind == 1) ? Wk : (kind == 2) ? Wv
                    : (kind == 3) ? Wo : Wf;
    unsigned short* dh = wpack + (size_t)mat * 32768;
    unsigned short* dl = dh + 16384;
    for (int f = threadIdx.x; f < 16384; f += 256) {
        int e    = f & 7;
        int lane = (f >> 3) & 63;
        int tj   = (f >> 9) & 7;
        int kc   = f >> 12;
        int row  = kc * 32 + ((lane >> 4) << 3) + e;
        int col  = tj * 16 + (lane & 15);
        float x  = ldT<BF16>(src, (l * NF + row) * NF + col);
        unsigned short hi = f2bf(x);
        unsigned short lo = f2bf(x - bf2f(hi));
        dh[f] = hi; dl[f] = lo;
    }
}

template<bool BF16>
__global__ __launch_bounds__(NTH)
void gnn_fused(const void* __restrict__ coords,
               const int* __restrict__ species,
               const unsigned char* __restrict__ maskraw,
               const void* __restrict__ embed,
               const void* __restrict__ Wq,          // dtype signature only
               const void* __restrict__ We,
               const void* __restrict__ bfb,
               const unsigned short* __restrict__ wpack,
               void* __restrict__ out)
{
    // ---- dtype signature check (block-uniform; wrong instantiation exits) ----
    {
        const unsigned int* w = (const unsigned int*)Wq;
        bool isbf = true;
        #pragma unroll
        for (int i = 0; i < 16; ++i) {
            unsigned int e = (w[i] >> 7) & 0xFFu;
            isbf = isbf && (e >= 0x60u && e <= 0x7Eu);
        }
        if (isbf != BF16) return;
    }

    extern __shared__ float smem[];
    unsigned short* a_hi = (unsigned short*)smem;        // 64*136 bf16
    unsigned short* a_lo = a_hi + NATOM * ASTRB;         // 64*136 bf16
    float* qm   = (float*)(a_lo + NATOM * ASTRB);        // 64*132 (q, then msg)
    float* kb   = qm + NATOM * STR;                      // 64*132 (k, then Wo/Wf out)
    float* vb   = kb + NATOM * STR;                      // 64*132
    float* ah   = vb + NATOM * STR;                      // 64*65 attn probs
    float* cs   = ah + NATOM * ASTR;                     // 64*4 coords
    float* wel  = cs + NATOM * 4;                        // 48 We (f32)
    int*   lenp = (int*)(wel + 48);

    const int t    = threadIdx.x;
    const int b    = blockIdx.x;
    const int fq   = t & 31;        // col group: cols fq*4..fq*4+3
    const int r0   = (t >> 5) * 4;  // rows r0..r0+3
    const int lane = t & 63;
    const int wave = t >> 6;

    // ---- init: coords, We, mask length ----
    if (t < 64) {
        cs[t * 4 + 0] = ldT<BF16>(coords, (b * NATOM + t) * 3 + 0);
        cs[t * 4 + 1] = ldT<BF16>(coords, (b * NATOM + t) * 3 + 1);
        cs[t * 4 + 2] = ldT<BF16>(coords, (b * NATOM + t) * 3 + 2);
    }
    if (t >= 64 && t < 64 + 42) wel[t - 64] = ldT<BF16>(We, t - 64);
    if (t < 64) {
        unsigned int w0 = *(const unsigned int*)maskraw;
        bool f;
        if (w0 == 1u)               f = ((const int*)maskraw)[b * NATOM + t] != 0;
        else if (w0 == 0x01010101u) f = maskraw[b * NATOM + t] != 0;
        else if (w0 == 0x3F800000u) f = ((const float*)maskraw)[b * NATOM + t] != 0.f;
        else                        f = ((const unsigned short*)maskraw)[b * NATOM + t] != 0;
        unsigned long long bal = __ballot(f);
        if (t == 0) *lenp = (int)__popcll(bal);
    }

    // ---- h0 = embed[species-1] ----
    float h[4][4];
    #pragma unroll
    for (int i = 0; i < 4; ++i) {
        int row = r0 + i;
        int sp = species[b * NATOM + row];
        float4 ev = ld4T<BF16>(embed, (sp - 1) * NF + fq * 4);
        h[i][0] = ev.x; h[i][1] = ev.y; h[i][2] = ev.z; h[i][3] = ev.w;
    }
    __syncthreads();
    const int len = *lenp;
    #pragma unroll
    for (int i = 0; i < 4; ++i)
        if (r0 + i >= len) { h[i][0] = 0.f; h[i][1] = 0.f; h[i][2] = 0.f; h[i][3] = 0.f; }

    float mu[4], rs[4];
    for (int l = 0; l < NLAYER; ++l) {
        // hn = LN(h) -> bf16 hi/lo A tiles (shuffle stats, no LDS round trip)
        ln_stats(h, mu, rs);
        write_a(h, mu, rs, a_hi, a_lo, r0, fq);
        __syncthreads();

        // q, k, v = hn @ W{q,k,v}[l] on MFMA
        mfma_mm(a_hi, a_lo, wpack + (size_t)(0 * 3 + l) * 32768, qm, lane, wave);
        mfma_mm(a_hi, a_lo, wpack + (size_t)(1 * 3 + l) * 32768, kb, lane, wave);
        mfma_mm(a_hi, a_lo, wpack + (size_t)(2 * 3 + l) * 32768, vb, lane, wave);
        __syncthreads();

        // ---- attention, per head (f32 VALU, unchanged) ----
        for (int hd = 0; hd < 2; ++hd) {
            const int hoff = hd * 64;
            const int n = t >> 3, mq = t & 7;
            float we_[7];
            #pragma unroll
            for (int e = 0; e < 7; ++e) we_[e] = wel[l * 14 + e * 2 + hd];
            float lg[8];
            #pragma unroll
            for (int j = 0; j < 8; ++j) lg[j] = 0.f;
            #pragma unroll
            for (int dc = 0; dc < 4; ++dc) {
                float qr[16];
                #pragma unroll
                for (int x = 0; x < 4; ++x) {
                    float4 v4 = *(const float4*)&qm[n * STR + hoff + dc * 16 + x * 4];
                    qr[x*4+0]=v4.x; qr[x*4+1]=v4.y; qr[x*4+2]=v4.z; qr[x*4+3]=v4.w;
                }
                #pragma unroll
                for (int j = 0; j < 8; ++j) {
                    const float* kp = &kb[(mq + 8 * j) * STR + hoff + dc * 16];
                    float s = 0.f;
                    #pragma unroll
                    for (int x = 0; x < 4; ++x) {
                        float4 k4 = *(const float4*)&kp[x * 4];
                        s += qr[x*4+0]*k4.x + qr[x*4+1]*k4.y + qr[x*4+2]*k4.z + qr[x*4+3]*k4.w;
                    }
                    lg[j] += s;
                }
            }
            float cnx = cs[n*4+0], cny = cs[n*4+1], cnz = cs[n*4+2];
            #pragma unroll
            for (int j = 0; j < 8; ++j) {
                int m = mq + 8 * j;
                float dx = cnx - cs[m*4+0];
                float dy = cny - cs[m*4+1];
                float dz = cnz - cs[m*4+2];
                float d = sqrtf(dx*dx + dy*dy + dz*dz + 1e-12f);
                float et = expf(-d);
                float s1 = 1.f / (1.f + 7.38905609893065f  * et);  // sigmoid(d-2)
                float s2 = 1.f / (1.f + 54.598150033144236f * et); // sigmoid(d-4)
                float s3 = 1.f / (1.f + 403.4287934927351f  * et); // sigmoid(d-6)
                lg[j] = lg[j] * 0.125f
                      + dx*we_[0] + dy*we_[1] + dz*we_[2] + d*we_[3]
                      + s1*we_[4] + s2*we_[5] + s3*we_[6];
            }
            // masked softmax over m (8 lanes per row)
            float mx = -3e38f;
            #pragma unroll
            for (int j = 0; j < 8; ++j) if (mq + 8*j < len) mx = fmaxf(mx, lg[j]);
            mx = fmaxf(mx, __shfl_xor(mx, 1));
            mx = fmaxf(mx, __shfl_xor(mx, 2));
            mx = fmaxf(mx, __shfl_xor(mx, 4));
            float sm = 0.f;
            #pragma unroll
            for (int j = 0; j < 8; ++j) {
                lg[j] = (mq + 8*j < len) ? expf(lg[j] - mx) : 0.f;
                sm += lg[j];
            }
            sm += __shfl_xor(sm, 1); sm += __shfl_xor(sm, 2); sm += __shfl_xor(sm, 4);
            float inv = (n < len) ? (1.f / sm) : 0.f;
            #pragma unroll
            for (int j = 0; j < 8; ++j) ah[n * ASTR + mq + 8*j] = lg[j] * inv;
            __syncthreads();

            // msg_h = attn_h @ v_h -> qm[:, hoff..hoff+63] (q of this head is dead)
            const int dcol = t & 63, rgm = t >> 6;  // 8 rows per thread
            float macc[8];
            #pragma unroll
            for (int i = 0; i < 8; ++i) macc[i] = 0.f;
            #pragma unroll 4
            for (int mc = 0; mc < 16; ++mc) {
                float v0 = vb[(mc*4+0) * STR + hoff + dcol];
                float v1 = vb[(mc*4+1) * STR + hoff + dcol];
                float v2 = vb[(mc*4+2) * STR + hoff + dcol];
                float v3 = vb[(mc*4+3) * STR + hoff + dcol];
                #pragma unroll
                for (int i = 0; i < 8; ++i) {
                    const float* ap = &ah[(rgm*8 + i) * ASTR + mc*4];
                    macc[i] += ap[0]*v0 + ap[1]*v1 + ap[2]*v2 + ap[3]*v3;
                }
            }
            #pragma unroll
            for (int i = 0; i < 8; ++i)
                qm[(rgm*8 + i) * STR + hoff + dcol] = macc[i];
            __syncthreads();
        }

        // msg -> bf16 hi/lo A tiles
        #pragma unroll
        for (int i = 0; i < 4; ++i) {
            float4 mv = *(const float4*)&qm[(r0 + i) * STR + fq * 4];
            ushort4 uh, ul;
            split4(mv, uh, ul);
            *(ushort4*)&a_hi[(r0 + i) * ASTRB + fq * 4] = uh;
            *(ushort4*)&a_lo[(r0 + i) * ASTRB + fq * 4] = ul;
        }
        __syncthreads();

        // h += msg @ Wo[l]  (MFMA into kb scratch; k is dead after logits)
        mfma_mm(a_hi, a_lo, wpack + (size_t)(3 * 3 + l) * 32768, kb, lane, wave);
        __syncthreads();
        #pragma unroll
        for (int i = 0; i < 4; ++i) {
            float4 ov = *(const float4*)&kb[(r0 + i) * STR + fq * 4];
            h[i][0] += ov.x; h[i][1] += ov.y; h[i][2] += ov.z; h[i][3] += ov.w;
        }

        // h += tanh(LN(h) @ Wf[l] + bf[l])
        ln_stats(h, mu, rs);
        write_a(h, mu, rs, a_hi, a_lo, r0, fq);
        __syncthreads();
        mfma_mm(a_hi, a_lo, wpack + (size_t)(4 * 3 + l) * 32768, kb, lane, wave);
        __syncthreads();
        {
            float4 bv = ld4T<BF16>(bfb, l * NF + fq * 4);
            #pragma unroll
            for (int i = 0; i < 4; ++i) {
                float4 fv = *(const float4*)&kb[(r0 + i) * STR + fq * 4];
                h[i][0] += tanhf(fv.x + bv.x);
                h[i][1] += tanhf(fv.y + bv.y);
                h[i][2] += tanhf(fv.z + bv.z);
                h[i][3] += tanhf(fv.w + bv.w);
            }
        }
        // h *= mask
        #pragma unroll
        for (int i = 0; i < 4; ++i)
            if (r0 + i >= len) { h[i][0]=0.f; h[i][1]=0.f; h[i][2]=0.f; h[i][3]=0.f; }
        // no trailing barrier needed: next write_a targets a-tiles, whose last
        // readers (Wf MFMA) finished before the sync above; kb's tanh readers
        // finish before the sync after next write_a.
    }

    // out = LN(h) in output dtype (direct store, shuffle stats)
    ln_stats(h, mu, rs);
    #pragma unroll
    for (int i = 0; i < 4; ++i) {
        int idx = b * NATOM * NF + (r0 + i) * NF + fq * 4;
        float o0 = (h[i][0]-mu[i])*rs[i], o1 = (h[i][1]-mu[i])*rs[i];
        float o2 = (h[i][2]-mu[i])*rs[i], o3 = (h[i][3]-mu[i])*rs[i];
        if constexpr (BF16) {
            ushort4 o;
            o.x = f2bf(o0); o.y = f2bf(o1); o.z = f2bf(o2); o.w = f2bf(o3);
            *(ushort4*)((unsigned short*)out + idx) = o;
        } else {
            *(float4*)((float*)out + idx) = make_float4(o0, o1, o2, o3);
        }
    }
}

static constexpr size_t SMEM_BYTES =
      (size_t)NATOM * ASTRB * 2 * 2       // a_hi + a_lo (bf16)
    + (size_t)NATOM * STR * 4 * 3         // qm, kb, vb (f32)
    + (size_t)NATOM * ASTR * 4            // ah
    + (size_t)NATOM * 4 * 4               // cs
    + 48 * 4                              // wel
    + 16;                                 // lenp (+pad)  => 154064 B < 160 KiB

extern "C" void kernel_launch(void* const* d_in, const int* in_sizes, int n_in,
                              void* d_out, int out_size, void* d_ws, size_t ws_size,
                              hipStream_t stream) {
    const void*           coords  = d_in[0];
    const int*            species = (const int*)d_in[1];
    const unsigned char*  maskraw = (const unsigned char*)d_in[2];
    const void*           embed   = d_in[3];
    const void*           Wq      = d_in[4];
    const void*           Wk      = d_in[5];
    const void*           Wv      = d_in[6];
    const void*           Wo      = d_in[7];
    const void*           We      = d_in[8];
    const void*           Wf      = d_in[9];
    const void*           bfb     = d_in[10];

    unsigned short* wpack = (unsigned short*)d_ws;   // 15 * 32768 ushorts = 960 KB

    (void)hipFuncSetAttribute((const void*)gnn_fused<true>,
                              hipFuncAttributeMaxDynamicSharedMemorySize,
                              (int)SMEM_BYTES);
    (void)hipFuncSetAttribute((const void*)gnn_fused<false>,
                              hipFuncAttributeMaxDynamicSharedMemorySize,
                              (int)SMEM_BYTES);

    prep_w<true ><<<dim3(15), dim3(256), 0, stream>>>(Wq, Wk, Wv, Wo, Wf, wpack);
    prep_w<false><<<dim3(15), dim3(256), 0, stream>>>(Wq, Wk, Wv, Wo, Wf, wpack);

    gnn_fused<true ><<<dim3(NBATCH), dim3(NTH), SMEM_BYTES, stream>>>(
        coords, species, maskraw, embed, Wq, We, bfb, wpack, d_out);
    gnn_fused<false><<<dim3(NBATCH), dim3(NTH), SMEM_BYTES, stream>>>(
        coords, species, maskraw, embed, Wq, We, bfb, wpack, d_out);
}

// Round 3
// 678.965 us; speedup vs baseline: 3.4365x; 1.9230x over previous
//
#include <hip/hip_runtime.h>

// NucleiGNN fused forward: B=2048 molecules, one block per molecule.
// ALL matmuls (q/k/v, QK^T, attn@V, Wo, Wf) run on MFMA via split-bf16
// (x = hi + lo; C ~= Ah*Bh + Al*Bh + Ah*Bl, f32 accumulate, ~1e-5 rel err).
// Weights pre-split+packed into MFMA B-fragment order in d_ws (prep kernel).
// q/k stored row-major [n][d] split-bf16 (B-frag of an NT GEMM == A layout);
// V stored transposed [d][m] so attn@V B-frags are contiguous; P (probs)
// is PER-HEAD [2][64][PSTR] (r2 bug: heads shared one buffer -> race).
// f32 scratch for Wo/Wf outputs overlays the dead K region.
// Softmax/edge-features/tanh/LN stay f32 VALU.

#define NBATCH 2048
#define NATOM  64
#define NF     128
#define NLAYER 3
#define STR    132   // f32 scratch row stride
#define ASTRB  136   // bf16 row-major tile stride (272B rows, 16B aligned)
#define VSTR   72    // vT row stride (144B rows, 16B aligned)
#define PSTR   72    // p row stride
#define NTH    512

using bf16x8 = __attribute__((ext_vector_type(8))) __bf16;
using f32x4  = __attribute__((ext_vector_type(4))) float;

__device__ __forceinline__ float bf2f(unsigned short u) {
    union { unsigned int i; float f; } v; v.i = ((unsigned int)u) << 16; return v.f;
}
__device__ __forceinline__ unsigned short f2bf(float f) {
    union { float ff; unsigned int i; } v; v.ff = f;
    unsigned int x = v.i;
    if ((x & 0x7f800000u) == 0x7f800000u) return (unsigned short)(x >> 16);
    return (unsigned short)((x + 0x7fffu + ((x >> 16) & 1u)) >> 16);
}

template<bool BF16>
__device__ __forceinline__ float ldT(const void* p, int i) {
    if constexpr (BF16) return bf2f(((const unsigned short*)p)[i]);
    else                return ((const float*)p)[i];
}
template<bool BF16>
__device__ __forceinline__ float4 ld4T(const void* p, int i) {
    if constexpr (BF16) {
        ushort4 v = *(const ushort4*)((const unsigned short*)p + i);
        return make_float4(bf2f(v.x), bf2f(v.y), bf2f(v.z), bf2f(v.w));
    } else {
        return *(const float4*)((const float*)p + i);
    }
}

__device__ __forceinline__ void split1(float x, unsigned short& h, unsigned short& l) {
    h = f2bf(x);
    l = f2bf(x - bf2f(h));
}

// LN row statistics from register tile h[4][4]; 32 consecutive lanes share a row.
__device__ __forceinline__ void ln_stats(const float (&h)[4][4], float (&mu)[4], float (&rs)[4]) {
    #pragma unroll
    for (int i = 0; i < 4; ++i) {
        float s  = h[i][0] + h[i][1] + h[i][2] + h[i][3];
        float s2 = h[i][0]*h[i][0] + h[i][1]*h[i][1] + h[i][2]*h[i][2] + h[i][3]*h[i][3];
        #pragma unroll
        for (int m = 1; m <= 16; m <<= 1) {
            s  += __shfl_xor(s,  m);
            s2 += __shfl_xor(s2, m);
        }
        float mm = s * (1.f / 128.f);
        float vv = s2 * (1.f / 128.f) - mm * mm;
        mu[i] = mm;
        rs[i] = rsqrtf(fmaxf(vv, 0.f) + 1e-5f);
    }
}

// normalize h with (mu,rs), split to bf16 hi/lo, store into A tiles
__device__ __forceinline__ void write_a(const float (&h)[4][4], const float (&mu)[4], const float (&rs)[4],
                                        unsigned short* __restrict__ a_hi, unsigned short* __restrict__ a_lo,
                                        int r0, int fq) {
    #pragma unroll
    for (int i = 0; i < 4; ++i) {
        #pragma unroll
        for (int jj = 0; jj < 4; ++jj) {
            float x = (h[i][jj] - mu[i]) * rs[i];
            unsigned short uh, ul;
            split1(x, uh, ul);
            a_hi[(r0 + i) * ASTRB + fq * 4 + jj] = uh;
            a_lo[(r0 + i) * ASTRB + fq * 4 + jj] = ul;
        }
    }
}

// Dense [64,128]x[128,128]: 2x2 tiles per wave. Wave w: rows 32*(w>>2)..+31,
// cols 32*(w&3)..+31. 3-term split-bf16. B from global wpack (hi | lo at +16384).
__device__ __forceinline__ void mfma_dense(const unsigned short* __restrict__ a_hi,
                                           const unsigned short* __restrict__ a_lo,
                                           const unsigned short* __restrict__ bp,
                                           f32x4 (&acc)[2][2], int lane, int wave)
{
    const int R0  = (wave >> 2) << 5;
    const int Cq2 = (wave & 3) << 1;     // tj base (in 16-col tiles)
    const int c = lane & 15, g = lane >> 4;
    const unsigned short* bl = bp + 16384;
    #pragma unroll
    for (int t2 = 0; t2 < 2; ++t2)
        #pragma unroll
        for (int j = 0; j < 2; ++j)
            acc[t2][j] = (f32x4){0.f, 0.f, 0.f, 0.f};
    #pragma unroll
    for (int kc = 0; kc < 4; ++kc) {
        const int ao = kc * 32 + (g << 3);
        bf16x8 a0h = *(const bf16x8*)&a_hi[(R0 + c) * ASTRB + ao];
        bf16x8 a0l = *(const bf16x8*)&a_lo[(R0 + c) * ASTRB + ao];
        bf16x8 a1h = *(const bf16x8*)&a_hi[(R0 + 16 + c) * ASTRB + ao];
        bf16x8 a1l = *(const bf16x8*)&a_lo[(R0 + 16 + c) * ASTRB + ao];
        #pragma unroll
        for (int j = 0; j < 2; ++j) {
            const int bi = ((((kc << 3) + Cq2 + j) << 6) + lane) << 3;
            bf16x8 bh = *(const bf16x8*)&bp[bi];
            bf16x8 bv = *(const bf16x8*)&bl[bi];
            acc[0][j] = __builtin_amdgcn_mfma_f32_16x16x32_bf16(a0h, bh, acc[0][j], 0, 0, 0);
            acc[0][j] = __builtin_amdgcn_mfma_f32_16x16x32_bf16(a0l, bh, acc[0][j], 0, 0, 0);
            acc[0][j] = __builtin_amdgcn_mfma_f32_16x16x32_bf16(a0h, bv, acc[0][j], 0, 0, 0);
            acc[1][j] = __builtin_amdgcn_mfma_f32_16x16x32_bf16(a1h, bh, acc[1][j], 0, 0, 0);
            acc[1][j] = __builtin_amdgcn_mfma_f32_16x16x32_bf16(a1l, bh, acc[1][j], 0, 0, 0);
            acc[1][j] = __builtin_amdgcn_mfma_f32_16x16x32_bf16(a1h, bv, acc[1][j], 0, 0, 0);
        }
    }
}

// C (2x2 tiles) -> split-bf16 row-major [64][ASTRB]
__device__ __forceinline__ void writeC_rm(const f32x4 (&acc)[2][2],
                                          unsigned short* __restrict__ hi,
                                          unsigned short* __restrict__ lo,
                                          int lane, int wave)
{
    const int R0 = (wave >> 2) << 5;
    const int C0 = (wave & 3) << 5;
    const int c = lane & 15, g4 = (lane >> 4) << 2;
    #pragma unroll
    for (int t2 = 0; t2 < 2; ++t2)
    #pragma unroll
    for (int j = 0; j < 2; ++j)
    #pragma unroll
    for (int r = 0; r < 4; ++r) {
        int idx = (R0 + 16*t2 + g4 + r) * ASTRB + C0 + 16*j + c;
        unsigned short h_, l_;
        split1(acc[t2][j][r], h_, l_);
        hi[idx] = h_; lo[idx] = l_;
    }
}

// C (2x2 tiles) -> split-bf16 TRANSPOSED vT[d][m]
__device__ __forceinline__ void writeC_vt(const f32x4 (&acc)[2][2],
                                          unsigned short* __restrict__ hi,
                                          unsigned short* __restrict__ lo,
                                          int lane, int wave)
{
    const int R0 = (wave >> 2) << 5;   // m rows
    const int C0 = (wave & 3) << 5;    // d cols
    const int c = lane & 15, g4 = (lane >> 4) << 2;
    #pragma unroll
    for (int t2 = 0; t2 < 2; ++t2)
    #pragma unroll
    for (int j = 0; j < 2; ++j)
    #pragma unroll
    for (int r = 0; r < 4; ++r) {
        int m = R0 + 16*t2 + g4 + r, d = C0 + 16*j + c;
        unsigned short h_, l_;
        split1(acc[t2][j][r], h_, l_);
        hi[d * VSTR + m] = h_; lo[d * VSTR + m] = l_;
    }
}

// C (2x2 tiles) -> f32 scratch [64][STR]
__device__ __forceinline__ void writeC_f32(const f32x4 (&acc)[2][2],
                                           float* __restrict__ dst, int lane, int wave)
{
    const int R0 = (wave >> 2) << 5;
    const int C0 = (wave & 3) << 5;
    const int c = lane & 15, g4 = (lane >> 4) << 2;
    #pragma unroll
    for (int t2 = 0; t2 < 2; ++t2)
    #pragma unroll
    for (int j = 0; j < 2; ++j)
    #pragma unroll
    for (int r = 0; r < 4; ++r)
        dst[(R0 + 16*t2 + g4 + r) * STR + C0 + 16*j + c] = acc[t2][j][r];
}

// Pre-split weights into bf16 hi/lo, packed in MFMA B-fragment order.
// Slot layout: wpack[(kind*3 + l)*32768]: [0,16384)=hi frags, [16384,32768)=lo.
// Fragment index f = ((kc*8 + tj)*64 + lane)*8 + e <->
//   W[l][kc*32 + (lane>>4)*8 + e][tj*16 + (lane&15)]
template<bool BF16>
__global__ __launch_bounds__(256)
void prep_w(const void* __restrict__ Wq, const void* __restrict__ Wk,
            const void* __restrict__ Wv, const void* __restrict__ Wo,
            const void* __restrict__ Wf, unsigned short* __restrict__ wpack)
{
    {
        const unsigned int* w = (const unsigned int*)Wq;
        bool isbf = true;
        #pragma unroll
        for (int i = 0; i < 16; ++i) {
            unsigned int e = (w[i] >> 7) & 0xFFu;
            isbf = isbf && (e >= 0x60u && e <= 0x7Eu);
        }
        if (isbf != BF16) return;
    }
    const int mat  = blockIdx.x;            // 0..14 = kind*3 + l
    const int kind = mat / 3, l = mat % 3;
    const void* src = (kind == 0) ? Wq : (kind == 1) ? Wk : (kind == 2) ? Wv
                    : (kind == 3) ? Wo : Wf;
    unsigned short* dh = wpack + (size_t)mat * 32768;
    unsigned short* dl = dh + 16384;
    for (int f = threadIdx.x; f < 16384; f += 256) {
        int e    = f & 7;
        int lane = (f >> 3) & 63;
        int tj   = (f >> 9) & 7;
        int kc   = f >> 12;
        int row  = kc * 32 + ((lane >> 4) << 3) + e;
        int col  = tj * 16 + (lane & 15);
        float x  = ldT<BF16>(src, (l * NF + row) * NF + col);
        unsigned short hi = f2bf(x);
        unsigned short lo = f2bf(x - bf2f(hi));
        dh[f] = hi; dl[f] = lo;
    }
}

template<bool BF16>
__global__ __launch_bounds__(NTH, 2)
void gnn_fused(const void* __restrict__ coords,
               const int* __restrict__ species,
               const unsigned char* __restrict__ maskraw,
               const void* __restrict__ embed,
               const void* __restrict__ Wq,          // dtype signature only
               const void* __restrict__ We,
               const void* __restrict__ bfb,
               const unsigned short* __restrict__ wpack,
               void* __restrict__ out)
{
    // ---- dtype signature check (block-uniform; wrong instantiation exits) ----
    {
        const unsigned int* w = (const unsigned int*)Wq;
        bool isbf = true;
        #pragma unroll
        for (int i = 0; i < 16; ++i) {
            unsigned int e = (w[i] >> 7) & 0xFFu;
            isbf = isbf && (e >= 0x60u && e <= 0x7Eu);
        }
        if (isbf != BF16) return;
    }

    extern __shared__ float smem[];
    unsigned short* a_hi  = (unsigned short*)smem;        // [64][136] (hn / q / msg / hn_ff)
    unsigned short* a_lo  = a_hi  + NATOM * ASTRB;
    unsigned short* k_hi  = a_lo  + NATOM * ASTRB;        // [64][136] k (scratch overlays)
    unsigned short* k_lo  = k_hi  + NATOM * ASTRB;
    unsigned short* vt_hi = k_lo  + NATOM * ASTRB;        // [128][72] v transposed
    unsigned short* vt_lo = vt_hi + NF * VSTR;
    unsigned short* p_hi  = vt_lo + NF * VSTR;            // [2][64][72] probs, PER HEAD
    unsigned short* p_lo  = p_hi  + 2 * NATOM * PSTR;
    float* scratch = (float*)k_hi;                        // [64][132] f32 (Wo/Wf out)
    float* cs   = (float*)(p_lo + 2 * NATOM * PSTR);      // 64*4 coords
    float* wel  = cs + NATOM * 4;                         // 48 We (f32)
    int*   lenp = (int*)(wel + 48);

    const int t    = threadIdx.x;
    const int b    = blockIdx.x;
    const int fq   = t & 31;        // col group for h tile: cols fq*4..fq*4+3
    const int r0   = (t >> 5) * 4;  // rows r0..r0+3
    const int lane = t & 63;
    const int wave = t >> 6;
    const int c    = lane & 15;
    const int g    = lane >> 4;
    const int g4   = g << 2;
    const int hd   = wave >> 2;          // attention head of this wave
    const int wb   = (wave & 3) << 4;    // attention row base of this wave
    unsigned short* ph_hd = p_hi + hd * NATOM * PSTR;
    unsigned short* pl_hd = p_lo + hd * NATOM * PSTR;

    // ---- init: coords, We, mask length ----
    if (t < 64) {
        cs[t * 4 + 0] = ldT<BF16>(coords, (b * NATOM + t) * 3 + 0);
        cs[t * 4 + 1] = ldT<BF16>(coords, (b * NATOM + t) * 3 + 1);
        cs[t * 4 + 2] = ldT<BF16>(coords, (b * NATOM + t) * 3 + 2);
    }
    if (t >= 64 && t < 64 + 42) wel[t - 64] = ldT<BF16>(We, t - 64);
    if (t < 64) {
        unsigned int w0 = *(const unsigned int*)maskraw;
        bool f;
        if (w0 == 1u)               f = ((const int*)maskraw)[b * NATOM + t] != 0;
        else if (w0 == 0x01010101u) f = maskraw[b * NATOM + t] != 0;
        else if (w0 == 0x3F800000u) f = ((const float*)maskraw)[b * NATOM + t] != 0.f;
        else                        f = ((const unsigned short*)maskraw)[b * NATOM + t] != 0;
        unsigned long long bal = __ballot(f);
        if (t == 0) *lenp = (int)__popcll(bal);
    }

    // ---- h0 = embed[species-1] ----
    float h[4][4];
    #pragma unroll
    for (int i = 0; i < 4; ++i) {
        int row = r0 + i;
        int sp = species[b * NATOM + row];
        float4 ev = ld4T<BF16>(embed, (sp - 1) * NF + fq * 4);
        h[i][0] = ev.x; h[i][1] = ev.y; h[i][2] = ev.z; h[i][3] = ev.w;
    }
    __syncthreads();
    const int len = *lenp;
    #pragma unroll
    for (int i = 0; i < 4; ++i)
        if (r0 + i >= len) { h[i][0] = 0.f; h[i][1] = 0.f; h[i][2] = 0.f; h[i][3] = 0.f; }

    float mu[4], rs[4];
    for (int l = 0; l < NLAYER; ++l) {
        // hn = LN(h) -> split-bf16 A tiles
        ln_stats(h, mu, rs);
        write_a(h, mu, rs, a_hi, a_lo, r0, fq);
        __syncthreads();                                        // B1

        // k = hn@Wk -> row-major tile; v = hn@Wv -> transposed tile
        {
            f32x4 kacc[2][2];
            mfma_dense(a_hi, a_lo, wpack + (size_t)(3 + l) * 32768, kacc, lane, wave);
            writeC_rm(kacc, k_hi, k_lo, lane, wave);
        }
        {
            f32x4 vacc[2][2];
            mfma_dense(a_hi, a_lo, wpack + (size_t)(6 + l) * 32768, vacc, lane, wave);
            writeC_vt(vacc, vt_hi, vt_lo, lane, wave);
        }
        // q = hn@Wq (held in regs; overwrites hn after all a-reads drain)
        f32x4 qacc[2][2];
        mfma_dense(a_hi, a_lo, wpack + (size_t)(0 + l) * 32768, qacc, lane, wave);
        __syncthreads();                                        // B2: a-reads done
        writeC_rm(qacc, a_hi, a_lo, lane, wave);
        __syncthreads();                                        // B3: q/k/vT visible

        // ---- logits = (q @ k^T)/8 + edge bias, via MFMA (NT: k row-major IS B-frag) ----
        f32x4 lacc[4];
        #pragma unroll
        for (int jt = 0; jt < 4; ++jt) lacc[jt] = (f32x4){0.f, 0.f, 0.f, 0.f};
        #pragma unroll
        for (int kc = 0; kc < 2; ++kc) {
            const int qo = (wb + c) * ASTRB + hd * 64 + kc * 32 + (g << 3);
            bf16x8 qh = *(const bf16x8*)&a_hi[qo];
            bf16x8 ql = *(const bf16x8*)&a_lo[qo];
            #pragma unroll
            for (int jt = 0; jt < 4; ++jt) {
                const int ko = (jt * 16 + c) * ASTRB + hd * 64 + kc * 32 + (g << 3);
                bf16x8 kh = *(const bf16x8*)&k_hi[ko];
                bf16x8 kl = *(const bf16x8*)&k_lo[ko];
                lacc[jt] = __builtin_amdgcn_mfma_f32_16x16x32_bf16(qh, kh, lacc[jt], 0, 0, 0);
                lacc[jt] = __builtin_amdgcn_mfma_f32_16x16x32_bf16(ql, kh, lacc[jt], 0, 0, 0);
                lacc[jt] = __builtin_amdgcn_mfma_f32_16x16x32_bf16(qh, kl, lacc[jt], 0, 0, 0);
            }
        }

        // ---- edge bias + masked softmax; lane holds rows wb+g4+r, cols 16*jt+c ----
        float we_[7];
        #pragma unroll
        for (int e = 0; e < 7; ++e) we_[e] = wel[l * 14 + e * 2 + hd];
        float cnx[4], cny[4], cnz[4];
        #pragma unroll
        for (int r = 0; r < 4; ++r) {
            int n = wb + g4 + r;
            cnx[r] = cs[n*4]; cny[r] = cs[n*4+1]; cnz[r] = cs[n*4+2];
        }
        float lg[4][4];
        #pragma unroll
        for (int jt = 0; jt < 4; ++jt) {
            int m = jt * 16 + c;
            float cmx = cs[m*4], cmy = cs[m*4+1], cmz = cs[m*4+2];
            #pragma unroll
            for (int r = 0; r < 4; ++r) {
                float dx = cnx[r] - cmx, dy = cny[r] - cmy, dz = cnz[r] - cmz;
                float d = sqrtf(dx*dx + dy*dy + dz*dz + 1e-12f);
                float et = expf(-d);
                float s1 = 1.f / (1.f + 7.38905609893065f  * et);  // sigmoid(d-2)
                float s2 = 1.f / (1.f + 54.598150033144236f * et); // sigmoid(d-4)
                float s3 = 1.f / (1.f + 403.4287934927351f  * et); // sigmoid(d-6)
                lg[jt][r] = lacc[jt][r] * 0.125f
                          + dx*we_[0] + dy*we_[1] + dz*we_[2] + d*we_[3]
                          + s1*we_[4] + s2*we_[5] + s3*we_[6];
            }
        }
        float mx[4] = {-3e38f, -3e38f, -3e38f, -3e38f};
        #pragma unroll
        for (int jt = 0; jt < 4; ++jt)
            if (jt * 16 + c < len) {
                #pragma unroll
                for (int r = 0; r < 4; ++r) mx[r] = fmaxf(mx[r], lg[jt][r]);
            }
        #pragma unroll
        for (int r = 0; r < 4; ++r) {
            mx[r] = fmaxf(mx[r], __shfl_xor(mx[r], 1));
            mx[r] = fmaxf(mx[r], __shfl_xor(mx[r], 2));
            mx[r] = fmaxf(mx[r], __shfl_xor(mx[r], 4));
            mx[r] = fmaxf(mx[r], __shfl_xor(mx[r], 8));
        }
        float sm[4] = {0.f, 0.f, 0.f, 0.f};
        #pragma unroll
        for (int jt = 0; jt < 4; ++jt) {
            bool vm = (jt * 16 + c) < len;
            #pragma unroll
            for (int r = 0; r < 4; ++r) {
                float e = vm ? expf(lg[jt][r] - mx[r]) : 0.f;
                lg[jt][r] = e; sm[r] += e;
            }
        }
        #pragma unroll
        for (int r = 0; r < 4; ++r) {
            sm[r] += __shfl_xor(sm[r], 1);
            sm[r] += __shfl_xor(sm[r], 2);
            sm[r] += __shfl_xor(sm[r], 4);
            sm[r] += __shfl_xor(sm[r], 8);
        }
        float inv[4];
        #pragma unroll
        for (int r = 0; r < 4; ++r) inv[r] = (wb + g4 + r < len) ? (1.f / sm[r]) : 0.f;
        // write probs (per-head buffer, wave-private rows) split-bf16
        #pragma unroll
        for (int jt = 0; jt < 4; ++jt)
            #pragma unroll
            for (int r = 0; r < 4; ++r) {
                unsigned short ph, pl2;
                split1(lg[jt][r] * inv[r], ph, pl2);
                ph_hd[(wb + g4 + r) * PSTR + jt * 16 + c] = ph;
                pl_hd[(wb + g4 + r) * PSTR + jt * 16 + c] = pl2;
            }
        __syncthreads();                                        // B4: logits q/k-reads done

        // ---- msg = P @ V via MFMA (vT gives contiguous B-frags) ----
        f32x4 macc[4];
        #pragma unroll
        for (int jt = 0; jt < 4; ++jt) macc[jt] = (f32x4){0.f, 0.f, 0.f, 0.f};
        #pragma unroll
        for (int kc = 0; kc < 2; ++kc) {
            const int po = (wb + c) * PSTR + kc * 32 + (g << 3);
            bf16x8 ph = *(const bf16x8*)&ph_hd[po];
            bf16x8 pl = *(const bf16x8*)&pl_hd[po];
            #pragma unroll
            for (int jt = 0; jt < 4; ++jt) {
                const int vo = (hd * 64 + jt * 16 + c) * VSTR + kc * 32 + (g << 3);
                bf16x8 vh = *(const bf16x8*)&vt_hi[vo];
                bf16x8 vl = *(const bf16x8*)&vt_lo[vo];
                macc[jt] = __builtin_amdgcn_mfma_f32_16x16x32_bf16(ph, vh, macc[jt], 0, 0, 0);
                macc[jt] = __builtin_amdgcn_mfma_f32_16x16x32_bf16(pl, vh, macc[jt], 0, 0, 0);
                macc[jt] = __builtin_amdgcn_mfma_f32_16x16x32_bf16(ph, vl, macc[jt], 0, 0, 0);
            }
        }
        // msg -> a-region (rows wb+g4+r, cols hd*64 + jt*16 + c), split-bf16
        #pragma unroll
        for (int jt = 0; jt < 4; ++jt)
            #pragma unroll
            for (int r = 0; r < 4; ++r) {
                unsigned short mh, ml;
                split1(macc[jt][r], mh, ml);
                int idx = (wb + g4 + r) * ASTRB + hd * 64 + jt * 16 + c;
                a_hi[idx] = mh; a_lo[idx] = ml;
            }
        __syncthreads();                                        // B5: msg visible

        // h += msg @ Wo[l]  (f32 scratch overlays dead k region)
        {
            f32x4 oacc[2][2];
            mfma_dense(a_hi, a_lo, wpack + (size_t)(9 + l) * 32768, oacc, lane, wave);
            writeC_f32(oacc, scratch, lane, wave);
        }
        __syncthreads();                                        // B6
        #pragma unroll
        for (int i = 0; i < 4; ++i) {
            float4 ov = *(const float4*)&scratch[(r0 + i) * STR + fq * 4];
            h[i][0] += ov.x; h[i][1] += ov.y; h[i][2] += ov.z; h[i][3] += ov.w;
        }

        // h += tanh(LN(h) @ Wf[l] + bf[l])
        ln_stats(h, mu, rs);
        write_a(h, mu, rs, a_hi, a_lo, r0, fq);
        __syncthreads();                                        // B7
        {
            f32x4 facc[2][2];
            mfma_dense(a_hi, a_lo, wpack + (size_t)(12 + l) * 32768, facc, lane, wave);
            writeC_f32(facc, scratch, lane, wave);
        }
        __syncthreads();                                        // B8
        {
            float4 bv = ld4T<BF16>(bfb, l * NF + fq * 4);
            #pragma unroll
            for (int i = 0; i < 4; ++i) {
                float4 fv = *(const float4*)&scratch[(r0 + i) * STR + fq * 4];
                h[i][0] += tanhf(fv.x + bv.x);
                h[i][1] += tanhf(fv.y + bv.y);
                h[i][2] += tanhf(fv.z + bv.z);
                h[i][3] += tanhf(fv.w + bv.w);
            }
        }
        // h *= mask
        #pragma unroll
        for (int i = 0; i < 4; ++i)
            if (r0 + i >= len) { h[i][0]=0.f; h[i][1]=0.f; h[i][2]=0.f; h[i][3]=0.f; }
        // next write_a is safe: all Wf a-reads finished before B8; scratch
        // readers (tanh) touch the k region, not the a region.
    }

    // out = LN(h) in output dtype (direct store, shuffle stats)
    ln_stats(h, mu, rs);
    #pragma unroll
    for (int i = 0; i < 4; ++i) {
        int idx = b * NATOM * NF + (r0 + i) * NF + fq * 4;
        float o0 = (h[i][0]-mu[i])*rs[i], o1 = (h[i][1]-mu[i])*rs[i];
        float o2 = (h[i][2]-mu[i])*rs[i], o3 = (h[i][3]-mu[i])*rs[i];
        if constexpr (BF16) {
            ushort4 o;
            o.x = f2bf(o0); o.y = f2bf(o1); o.z = f2bf(o2); o.w = f2bf(o3);
            *(ushort4*)((unsigned short*)out + idx) = o;
        } else {
            *(float4*)((float*)out + idx) = make_float4(o0, o1, o2, o3);
        }
    }
}

static constexpr size_t SMEM_BYTES =
      (size_t)NATOM * ASTRB * 2 * 2       // a_hi + a_lo
    + (size_t)NATOM * ASTRB * 2 * 2       // k_hi + k_lo (scratch overlays: 33792 <= 34816)
    + (size_t)NF * VSTR * 2 * 2           // vt_hi + vt_lo
    + (size_t)2 * NATOM * PSTR * 2 * 2    // p_hi + p_lo, per head
    + (size_t)NATOM * 4 * 4               // cs
    + 48 * 4                              // wel
    + 16;                                 // lenp (+pad)  => 144592 B

extern "C" void kernel_launch(void* const* d_in, const int* in_sizes, int n_in,
                              void* d_out, int out_size, void* d_ws, size_t ws_size,
                              hipStream_t stream) {
    const void*           coords  = d_in[0];
    const int*            species = (const int*)d_in[1];
    const unsigned char*  maskraw = (const unsigned char*)d_in[2];
    const void*           embed   = d_in[3];
    const void*           Wq      = d_in[4];
    const void*           Wk      = d_in[5];
    const void*           Wv      = d_in[6];
    const void*           Wo      = d_in[7];
    const void*           We      = d_in[8];
    const void*           Wf      = d_in[9];
    const void*           bfb     = d_in[10];

    unsigned short* wpack = (unsigned short*)d_ws;   // 15 * 32768 ushorts = 960 KB

    (void)hipFuncSetAttribute((const void*)gnn_fused<true>,
                              hipFuncAttributeMaxDynamicSharedMemorySize,
                              (int)SMEM_BYTES);
    (void)hipFuncSetAttribute((const void*)gnn_fused<false>,
                              hipFuncAttributeMaxDynamicSharedMemorySize,
                              (int)SMEM_BYTES);

    prep_w<true ><<<dim3(15), dim3(256), 0, stream>>>(Wq, Wk, Wv, Wo, Wf, wpack);
    prep_w<false><<<dim3(15), dim3(256), 0, stream>>>(Wq, Wk, Wv, Wo, Wf, wpack);

    gnn_fused<true ><<<dim3(NBATCH), dim3(NTH), SMEM_BYTES, stream>>>(
        coords, species, maskraw, embed, Wq, We, bfb, wpack, d_out);
    gnn_fused<false><<<dim3(NBATCH), dim3(NTH), SMEM_BYTES, stream>>>(
        coords, species, maskraw, embed, Wq, We, bfb, wpack, d_out);
}

// Round 4
// 491.930 us; speedup vs baseline: 4.7431x; 1.3802x over previous
//
#include <hip/hip_runtime.h>

// NucleiGNN fused forward: B=2048 molecules, one block per molecule.
// ALL matmuls (q/k/v, QK^T, attn@V, Wo, Wf) run on MFMA via split-bf16
// (x = hi + lo; C ~= Ah*Bh + Al*Bh [+ Ah*Bl], f32 accumulate).
// In the BF16-input instantiation the weights are EXACTLY bf16, so lo(W)=0
// and the Ah*Bl term is skipped at compile time (WLO=false).
// Splits use native __bf16 casts (v_cvt_pk_bf16_f32), edge features
// (d, sigmoids) are hoisted out of the layer loop into registers, and
// transcendentals use native v_exp/v_rcp/v_sqrt approximations.
// q/k stored row-major [n][d] split-bf16 (B-frag of an NT GEMM == A layout);
// V stored transposed [d][m]; P (probs) per-head [2][64][PSTR].
// f32 scratch for Wo/Wf outputs overlays the dead K region.

#define NBATCH 2048
#define NATOM  64
#define NF     128
#define NLAYER 3
#define STR    132   // f32 scratch row stride
#define ASTRB  136   // bf16 row-major tile stride (272B rows, 16B aligned)
#define VSTR   72    // vT row stride (144B rows, 16B aligned)
#define PSTR   72    // p row stride
#define NTH    512

using bf16x8 = __attribute__((ext_vector_type(8))) __bf16;
using f32x4  = __attribute__((ext_vector_type(4))) float;

__device__ __forceinline__ float bf2f(unsigned short u) {
    union { unsigned int i; float f; } v; v.i = ((unsigned int)u) << 16; return v.f;
}
__device__ __forceinline__ unsigned short f2bf(float f) {
    union { float ff; unsigned int i; } v; v.ff = f;
    unsigned int x = v.i;
    if ((x & 0x7f800000u) == 0x7f800000u) return (unsigned short)(x >> 16);
    return (unsigned short)((x + 0x7fffu + ((x >> 16) & 1u)) >> 16);
}
__device__ __forceinline__ unsigned short bfbits(float x) {
    union { __bf16 b; unsigned short u; } v; v.b = (__bf16)x; return v.u;
}

__device__ __forceinline__ float fast_rcp(float x)  { return __builtin_amdgcn_rcpf(x); }
__device__ __forceinline__ float fast_sqrt(float x) { return __builtin_amdgcn_sqrtf(x); }
__device__ __forceinline__ float fast_exp(float x)  { return __builtin_amdgcn_exp2f(x * 1.4426950408889634f); }

template<bool BF16>
__device__ __forceinline__ float ldT(const void* p, int i) {
    if constexpr (BF16) return bf2f(((const unsigned short*)p)[i]);
    else                return ((const float*)p)[i];
}
template<bool BF16>
__device__ __forceinline__ float4 ld4T(const void* p, int i) {
    if constexpr (BF16) {
        ushort4 v = *(const ushort4*)((const unsigned short*)p + i);
        return make_float4(bf2f(v.x), bf2f(v.y), bf2f(v.z), bf2f(v.w));
    } else {
        return *(const float4*)((const float*)p + i);
    }
}

// native split: hi = RNE bf16 of x, lo = RNE bf16 of residual
__device__ __forceinline__ void split1(float x, __bf16& h, __bf16& l) {
    h = (__bf16)x;
    l = (__bf16)(x - (float)h);
}

// LN row statistics from register tile h[4][4]; 32 consecutive lanes share a row.
__device__ __forceinline__ void ln_stats(const float (&h)[4][4], float (&mu)[4], float (&rs)[4]) {
    #pragma unroll
    for (int i = 0; i < 4; ++i) {
        float s  = h[i][0] + h[i][1] + h[i][2] + h[i][3];
        float s2 = h[i][0]*h[i][0] + h[i][1]*h[i][1] + h[i][2]*h[i][2] + h[i][3]*h[i][3];
        #pragma unroll
        for (int m = 1; m <= 16; m <<= 1) {
            s  += __shfl_xor(s,  m);
            s2 += __shfl_xor(s2, m);
        }
        float mm = s * (1.f / 128.f);
        float vv = s2 * (1.f / 128.f) - mm * mm;
        mu[i] = mm;
        rs[i] = rsqrtf(fmaxf(vv, 0.f) + 1e-5f);
    }
}

// normalize h with (mu,rs), split to bf16 hi/lo, store into A tiles
__device__ __forceinline__ void write_a(const float (&h)[4][4], const float (&mu)[4], const float (&rs)[4],
                                        __bf16* __restrict__ a_hi, __bf16* __restrict__ a_lo,
                                        int r0, int fq) {
    #pragma unroll
    for (int i = 0; i < 4; ++i) {
        #pragma unroll
        for (int jj = 0; jj < 4; ++jj) {
            float x = (h[i][jj] - mu[i]) * rs[i];
            __bf16 uh, ul;
            split1(x, uh, ul);
            a_hi[(r0 + i) * ASTRB + fq * 4 + jj] = uh;
            a_lo[(r0 + i) * ASTRB + fq * 4 + jj] = ul;
        }
    }
}

// Dense [64,128]x[128,128]: 2x2 tiles per wave. Wave w: rows 32*(w>>2)..+31,
// cols 32*(w&3)..+31. B from global wpack (hi | lo at +16384).
// WLO: include the Ah*Bl term (false when weights are exactly bf16 -> lo==0).
template<bool WLO>
__device__ __forceinline__ void mfma_dense(const __bf16* __restrict__ a_hi,
                                           const __bf16* __restrict__ a_lo,
                                           const __bf16* __restrict__ bp,
                                           f32x4 (&acc)[2][2], int lane, int wave)
{
    const int R0  = (wave >> 2) << 5;
    const int Cq2 = (wave & 3) << 1;     // tj base (in 16-col tiles)
    const int c = lane & 15, g = lane >> 4;
    const __bf16* bl = bp + 16384;
    #pragma unroll
    for (int t2 = 0; t2 < 2; ++t2)
        #pragma unroll
        for (int j = 0; j < 2; ++j)
            acc[t2][j] = (f32x4){0.f, 0.f, 0.f, 0.f};
    #pragma unroll
    for (int kc = 0; kc < 4; ++kc) {
        const int ao = kc * 32 + (g << 3);
        bf16x8 a0h = *(const bf16x8*)&a_hi[(R0 + c) * ASTRB + ao];
        bf16x8 a0l = *(const bf16x8*)&a_lo[(R0 + c) * ASTRB + ao];
        bf16x8 a1h = *(const bf16x8*)&a_hi[(R0 + 16 + c) * ASTRB + ao];
        bf16x8 a1l = *(const bf16x8*)&a_lo[(R0 + 16 + c) * ASTRB + ao];
        #pragma unroll
        for (int j = 0; j < 2; ++j) {
            const int bi = ((((kc << 3) + Cq2 + j) << 6) + lane) << 3;
            bf16x8 bh = *(const bf16x8*)&bp[bi];
            acc[0][j] = __builtin_amdgcn_mfma_f32_16x16x32_bf16(a0h, bh, acc[0][j], 0, 0, 0);
            acc[0][j] = __builtin_amdgcn_mfma_f32_16x16x32_bf16(a0l, bh, acc[0][j], 0, 0, 0);
            acc[1][j] = __builtin_amdgcn_mfma_f32_16x16x32_bf16(a1h, bh, acc[1][j], 0, 0, 0);
            acc[1][j] = __builtin_amdgcn_mfma_f32_16x16x32_bf16(a1l, bh, acc[1][j], 0, 0, 0);
            if constexpr (WLO) {
                bf16x8 bv = *(const bf16x8*)&bl[bi];
                acc[0][j] = __builtin_amdgcn_mfma_f32_16x16x32_bf16(a0h, bv, acc[0][j], 0, 0, 0);
                acc[1][j] = __builtin_amdgcn_mfma_f32_16x16x32_bf16(a1h, bv, acc[1][j], 0, 0, 0);
            }
        }
    }
}

// C (2x2 tiles) -> split-bf16 row-major [64][ASTRB]
__device__ __forceinline__ void writeC_rm(const f32x4 (&acc)[2][2],
                                          __bf16* __restrict__ hi,
                                          __bf16* __restrict__ lo,
                                          int lane, int wave)
{
    const int R0 = (wave >> 2) << 5;
    const int C0 = (wave & 3) << 5;
    const int c = lane & 15, g4 = (lane >> 4) << 2;
    #pragma unroll
    for (int t2 = 0; t2 < 2; ++t2)
    #pragma unroll
    for (int j = 0; j < 2; ++j)
    #pragma unroll
    for (int r = 0; r < 4; ++r) {
        int idx = (R0 + 16*t2 + g4 + r) * ASTRB + C0 + 16*j + c;
        __bf16 h_, l_;
        split1(acc[t2][j][r], h_, l_);
        hi[idx] = h_; lo[idx] = l_;
    }
}

// C (2x2 tiles) -> split-bf16 TRANSPOSED vT[d][m]
__device__ __forceinline__ void writeC_vt(const f32x4 (&acc)[2][2],
                                          __bf16* __restrict__ hi,
                                          __bf16* __restrict__ lo,
                                          int lane, int wave)
{
    const int R0 = (wave >> 2) << 5;   // m rows
    const int C0 = (wave & 3) << 5;    // d cols
    const int c = lane & 15, g4 = (lane >> 4) << 2;
    #pragma unroll
    for (int t2 = 0; t2 < 2; ++t2)
    #pragma unroll
    for (int j = 0; j < 2; ++j)
    #pragma unroll
    for (int r = 0; r < 4; ++r) {
        int m = R0 + 16*t2 + g4 + r, d = C0 + 16*j + c;
        __bf16 h_, l_;
        split1(acc[t2][j][r], h_, l_);
        hi[d * VSTR + m] = h_; lo[d * VSTR + m] = l_;
    }
}

// C (2x2 tiles) -> f32 scratch [64][STR]
__device__ __forceinline__ void writeC_f32(const f32x4 (&acc)[2][2],
                                           float* __restrict__ dst, int lane, int wave)
{
    const int R0 = (wave >> 2) << 5;
    const int C0 = (wave & 3) << 5;
    const int c = lane & 15, g4 = (lane >> 4) << 2;
    #pragma unroll
    for (int t2 = 0; t2 < 2; ++t2)
    #pragma unroll
    for (int j = 0; j < 2; ++j)
    #pragma unroll
    for (int r = 0; r < 4; ++r)
        dst[(R0 + 16*t2 + g4 + r) * STR + C0 + 16*j + c] = acc[t2][j][r];
}

// Pre-split weights into bf16 hi/lo, packed in MFMA B-fragment order.
// Slot layout: wpack[(kind*3 + l)*32768]: [0,16384)=hi frags, [16384,32768)=lo.
// Fragment index f = ((kc*8 + tj)*64 + lane)*8 + e <->
//   W[l][kc*32 + (lane>>4)*8 + e][tj*16 + (lane&15)]
template<bool BF16>
__global__ __launch_bounds__(256)
void prep_w(const void* __restrict__ Wq, const void* __restrict__ Wk,
            const void* __restrict__ Wv, const void* __restrict__ Wo,
            const void* __restrict__ Wf, unsigned short* __restrict__ wpack)
{
    {
        const unsigned int* w = (const unsigned int*)Wq;
        bool isbf = true;
        #pragma unroll
        for (int i = 0; i < 16; ++i) {
            unsigned int e = (w[i] >> 7) & 0xFFu;
            isbf = isbf && (e >= 0x60u && e <= 0x7Eu);
        }
        if (isbf != BF16) return;
    }
    const int mat  = blockIdx.x;            // 0..14 = kind*3 + l
    const int kind = mat / 3, l = mat % 3;
    const void* src = (kind == 0) ? Wq : (kind == 1) ? Wk : (kind == 2) ? Wv
                    : (kind == 3) ? Wo : Wf;
    unsigned short* dh = wpack + (size_t)mat * 32768;
    unsigned short* dl = dh + 16384;
    for (int f = threadIdx.x; f < 16384; f += 256) {
        int e    = f & 7;
        int lane = (f >> 3) & 63;
        int tj   = (f >> 9) & 7;
        int kc   = f >> 12;
        int row  = kc * 32 + ((lane >> 4) << 3) + e;
        int col  = tj * 16 + (lane & 15);
        float x  = ldT<BF16>(src, (l * NF + row) * NF + col);
        unsigned short hi = f2bf(x);
        unsigned short lo = f2bf(x - bf2f(hi));
        dh[f] = hi; dl[f] = lo;
    }
}

template<bool BF16>
__global__ __launch_bounds__(NTH, 2)
void gnn_fused(const void* __restrict__ coords,
               const int* __restrict__ species,
               const unsigned char* __restrict__ maskraw,
               const void* __restrict__ embed,
               const void* __restrict__ Wq,          // dtype signature only
               const void* __restrict__ We,
               const void* __restrict__ bfb,
               const unsigned short* __restrict__ wpack,
               void* __restrict__ out)
{
    // ---- dtype signature check (block-uniform; wrong instantiation exits) ----
    {
        const unsigned int* w = (const unsigned int*)Wq;
        bool isbf = true;
        #pragma unroll
        for (int i = 0; i < 16; ++i) {
            unsigned int e = (w[i] >> 7) & 0xFFu;
            isbf = isbf && (e >= 0x60u && e <= 0x7Eu);
        }
        if (isbf != BF16) return;
    }

    extern __shared__ float smem[];
    __bf16* a_hi  = (__bf16*)smem;                  // [64][136] (hn / q / msg / hn_ff)
    __bf16* a_lo  = a_hi  + NATOM * ASTRB;
    __bf16* k_hi  = a_lo  + NATOM * ASTRB;          // [64][136] k (scratch overlays)
    __bf16* k_lo  = k_hi  + NATOM * ASTRB;
    __bf16* vt_hi = k_lo  + NATOM * ASTRB;          // [128][72] v transposed
    __bf16* vt_lo = vt_hi + NF * VSTR;
    __bf16* p_hi  = vt_lo + NF * VSTR;              // [2][64][72] probs, PER HEAD
    __bf16* p_lo  = p_hi  + 2 * NATOM * PSTR;
    float* scratch = (float*)k_hi;                  // [64][132] f32 (Wo/Wf out)
    float* cs   = (float*)(p_lo + 2 * NATOM * PSTR);// 64*4 coords
    float* wel  = cs + NATOM * 4;                   // 48 We (f32)
    int*   lenp = (int*)(wel + 48);

    const int t    = threadIdx.x;
    const int b    = blockIdx.x;
    const int fq   = t & 31;        // col group for h tile: cols fq*4..fq*4+3
    const int r0   = (t >> 5) * 4;  // rows r0..r0+3
    const int lane = t & 63;
    const int wave = t >> 6;
    const int c    = lane & 15;
    const int g    = lane >> 4;
    const int g4   = g << 2;
    const int hd   = wave >> 2;          // attention head of this wave
    const int wb   = (wave & 3) << 4;    // attention row base of this wave
    __bf16* ph_hd = p_hi + hd * NATOM * PSTR;
    __bf16* pl_hd = p_lo + hd * NATOM * PSTR;

    // ---- init: coords, We, mask length ----
    if (t < 64) {
        cs[t * 4 + 0] = ldT<BF16>(coords, (b * NATOM + t) * 3 + 0);
        cs[t * 4 + 1] = ldT<BF16>(coords, (b * NATOM + t) * 3 + 1);
        cs[t * 4 + 2] = ldT<BF16>(coords, (b * NATOM + t) * 3 + 2);
    }
    if (t >= 64 && t < 64 + 42) wel[t - 64] = ldT<BF16>(We, t - 64);
    if (t < 64) {
        unsigned int w0 = *(const unsigned int*)maskraw;
        bool f;
        if (w0 == 1u)               f = ((const int*)maskraw)[b * NATOM + t] != 0;
        else if (w0 == 0x01010101u) f = maskraw[b * NATOM + t] != 0;
        else if (w0 == 0x3F800000u) f = ((const float*)maskraw)[b * NATOM + t] != 0.f;
        else                        f = ((const unsigned short*)maskraw)[b * NATOM + t] != 0;
        unsigned long long bal = __ballot(f);
        if (t == 0) *lenp = (int)__popcll(bal);
    }

    // ---- h0 = embed[species-1] ----
    float h[4][4];
    #pragma unroll
    for (int i = 0; i < 4; ++i) {
        int row = r0 + i;
        int sp = species[b * NATOM + row];
        float4 ev = ld4T<BF16>(embed, (sp - 1) * NF + fq * 4);
        h[i][0] = ev.x; h[i][1] = ev.y; h[i][2] = ev.z; h[i][3] = ev.w;
    }
    __syncthreads();
    const int len = *lenp;
    #pragma unroll
    for (int i = 0; i < 4; ++i)
        if (r0 + i >= len) { h[i][0] = 0.f; h[i][1] = 0.f; h[i][2] = 0.f; h[i][3] = 0.f; }

    // ---- precompute layer-invariant edge features for this lane's 16 pairs ----
    // pair (jt,r): row n = wb+g4+r, col m = jt*16+c
    float pd[4][4], ps1[4][4], ps2[4][4], ps3[4][4];
    {
        float cnx[4], cny[4], cnz[4];
        #pragma unroll
        for (int r = 0; r < 4; ++r) {
            int n = wb + g4 + r;
            cnx[r] = cs[n*4]; cny[r] = cs[n*4+1]; cnz[r] = cs[n*4+2];
        }
        #pragma unroll
        for (int jt = 0; jt < 4; ++jt) {
            int m = jt * 16 + c;
            float cmx = cs[m*4], cmy = cs[m*4+1], cmz = cs[m*4+2];
            #pragma unroll
            for (int r = 0; r < 4; ++r) {
                float dx = cnx[r] - cmx, dy = cny[r] - cmy, dz = cnz[r] - cmz;
                float d = fast_sqrt(dx*dx + dy*dy + dz*dz + 1e-12f);
                float et = fast_exp(-d);
                pd[jt][r]  = d;
                ps1[jt][r] = fast_rcp(1.f + 7.38905609893065f   * et);  // sigmoid(d-2)
                ps2[jt][r] = fast_rcp(1.f + 54.598150033144236f * et);  // sigmoid(d-4)
                ps3[jt][r] = fast_rcp(1.f + 403.4287934927351f  * et);  // sigmoid(d-6)
            }
        }
    }

    float mu[4], rs[4];
    for (int l = 0; l < NLAYER; ++l) {
        // hn = LN(h) -> split-bf16 A tiles
        ln_stats(h, mu, rs);
        write_a(h, mu, rs, a_hi, a_lo, r0, fq);
        __syncthreads();                                        // B1

        // k = hn@Wk -> row-major tile; v = hn@Wv -> transposed tile
        {
            f32x4 kacc[2][2];
            mfma_dense<!BF16>(a_hi, a_lo, (const __bf16*)wpack + (size_t)(3 + l) * 32768, kacc, lane, wave);
            writeC_rm(kacc, k_hi, k_lo, lane, wave);
        }
        {
            f32x4 vacc[2][2];
            mfma_dense<!BF16>(a_hi, a_lo, (const __bf16*)wpack + (size_t)(6 + l) * 32768, vacc, lane, wave);
            writeC_vt(vacc, vt_hi, vt_lo, lane, wave);
        }
        // q = hn@Wq (held in regs; overwrites hn after all a-reads drain)
        f32x4 qacc[2][2];
        mfma_dense<!BF16>(a_hi, a_lo, (const __bf16*)wpack + (size_t)(0 + l) * 32768, qacc, lane, wave);
        __syncthreads();                                        // B2: a-reads done
        writeC_rm(qacc, a_hi, a_lo, lane, wave);
        __syncthreads();                                        // B3: q/k/vT visible

        // ---- logits = (q @ k^T)/8 + edge bias, via MFMA (NT: k row-major IS B-frag) ----
        f32x4 lacc[4];
        #pragma unroll
        for (int jt = 0; jt < 4; ++jt) lacc[jt] = (f32x4){0.f, 0.f, 0.f, 0.f};
        #pragma unroll
        for (int kc = 0; kc < 2; ++kc) {
            const int qo = (wb + c) * ASTRB + hd * 64 + kc * 32 + (g << 3);
            bf16x8 qh = *(const bf16x8*)&a_hi[qo];
            bf16x8 ql = *(const bf16x8*)&a_lo[qo];
            #pragma unroll
            for (int jt = 0; jt < 4; ++jt) {
                const int ko = (jt * 16 + c) * ASTRB + hd * 64 + kc * 32 + (g << 3);
                bf16x8 kh = *(const bf16x8*)&k_hi[ko];
                bf16x8 kl = *(const bf16x8*)&k_lo[ko];
                lacc[jt] = __builtin_amdgcn_mfma_f32_16x16x32_bf16(qh, kh, lacc[jt], 0, 0, 0);
                lacc[jt] = __builtin_amdgcn_mfma_f32_16x16x32_bf16(ql, kh, lacc[jt], 0, 0, 0);
                lacc[jt] = __builtin_amdgcn_mfma_f32_16x16x32_bf16(qh, kl, lacc[jt], 0, 0, 0);
            }
        }

        // ---- edge bias (precomputed features) + masked softmax ----
        float we_[7];
        #pragma unroll
        for (int e = 0; e < 7; ++e) we_[e] = wel[l * 14 + e * 2 + hd];
        float cnx[4], cny[4], cnz[4];
        #pragma unroll
        for (int r = 0; r < 4; ++r) {
            int n = wb + g4 + r;
            cnx[r] = cs[n*4]; cny[r] = cs[n*4+1]; cnz[r] = cs[n*4+2];
        }
        float lg[4][4];
        #pragma unroll
        for (int jt = 0; jt < 4; ++jt) {
            int m = jt * 16 + c;
            float cmx = cs[m*4], cmy = cs[m*4+1], cmz = cs[m*4+2];
            #pragma unroll
            for (int r = 0; r < 4; ++r) {
                float dx = cnx[r] - cmx, dy = cny[r] - cmy, dz = cnz[r] - cmz;
                lg[jt][r] = lacc[jt][r] * 0.125f
                          + dx*we_[0] + dy*we_[1] + dz*we_[2]
                          + pd[jt][r]*we_[3]
                          + ps1[jt][r]*we_[4] + ps2[jt][r]*we_[5] + ps3[jt][r]*we_[6];
            }
        }
        float mx[4] = {-3e38f, -3e38f, -3e38f, -3e38f};
        #pragma unroll
        for (int jt = 0; jt < 4; ++jt)
            if (jt * 16 + c < len) {
                #pragma unroll
                for (int r = 0; r < 4; ++r) mx[r] = fmaxf(mx[r], lg[jt][r]);
            }
        #pragma unroll
        for (int r = 0; r < 4; ++r) {
            mx[r] = fmaxf(mx[r], __shfl_xor(mx[r], 1));
            mx[r] = fmaxf(mx[r], __shfl_xor(mx[r], 2));
            mx[r] = fmaxf(mx[r], __shfl_xor(mx[r], 4));
            mx[r] = fmaxf(mx[r], __shfl_xor(mx[r], 8));
        }
        float sm[4] = {0.f, 0.f, 0.f, 0.f};
        #pragma unroll
        for (int jt = 0; jt < 4; ++jt) {
            bool vm = (jt * 16 + c) < len;
            #pragma unroll
            for (int r = 0; r < 4; ++r) {
                float e = vm ? fast_exp(lg[jt][r] - mx[r]) : 0.f;
                lg[jt][r] = e; sm[r] += e;
            }
        }
        #pragma unroll
        for (int r = 0; r < 4; ++r) {
            sm[r] += __shfl_xor(sm[r], 1);
            sm[r] += __shfl_xor(sm[r], 2);
            sm[r] += __shfl_xor(sm[r], 4);
            sm[r] += __shfl_xor(sm[r], 8);
        }
        float inv[4];
        #pragma unroll
        for (int r = 0; r < 4; ++r)
            inv[r] = (wb + g4 + r < len) ? fast_rcp(sm[r]) : 0.f;
        // write probs (per-head buffer, wave-private rows) split-bf16
        #pragma unroll
        for (int jt = 0; jt < 4; ++jt)
            #pragma unroll
            for (int r = 0; r < 4; ++r) {
                __bf16 ph, pl2;
                split1(lg[jt][r] * inv[r], ph, pl2);
                ph_hd[(wb + g4 + r) * PSTR + jt * 16 + c] = ph;
                pl_hd[(wb + g4 + r) * PSTR + jt * 16 + c] = pl2;
            }
        __syncthreads();                                        // B4: logits q/k-reads done

        // ---- msg = P @ V via MFMA (vT gives contiguous B-frags) ----
        f32x4 macc[4];
        #pragma unroll
        for (int jt = 0; jt < 4; ++jt) macc[jt] = (f32x4){0.f, 0.f, 0.f, 0.f};
        #pragma unroll
        for (int kc = 0; kc < 2; ++kc) {
            const int po = (wb + c) * PSTR + kc * 32 + (g << 3);
            bf16x8 ph = *(const bf16x8*)&ph_hd[po];
            bf16x8 pl = *(const bf16x8*)&pl_hd[po];
            #pragma unroll
            for (int jt = 0; jt < 4; ++jt) {
                const int vo = (hd * 64 + jt * 16 + c) * VSTR + kc * 32 + (g << 3);
                bf16x8 vh = *(const bf16x8*)&vt_hi[vo];
                bf16x8 vl = *(const bf16x8*)&vt_lo[vo];
                macc[jt] = __builtin_amdgcn_mfma_f32_16x16x32_bf16(ph, vh, macc[jt], 0, 0, 0);
                macc[jt] = __builtin_amdgcn_mfma_f32_16x16x32_bf16(pl, vh, macc[jt], 0, 0, 0);
                macc[jt] = __builtin_amdgcn_mfma_f32_16x16x32_bf16(ph, vl, macc[jt], 0, 0, 0);
            }
        }
        // msg -> a-region (rows wb+g4+r, cols hd*64 + jt*16 + c), split-bf16
        #pragma unroll
        for (int jt = 0; jt < 4; ++jt)
            #pragma unroll
            for (int r = 0; r < 4; ++r) {
                __bf16 mh, ml;
                split1(macc[jt][r], mh, ml);
                int idx = (wb + g4 + r) * ASTRB + hd * 64 + jt * 16 + c;
                a_hi[idx] = mh; a_lo[idx] = ml;
            }
        __syncthreads();                                        // B5: msg visible

        // h += msg @ Wo[l]  (f32 scratch overlays dead k region)
        {
            f32x4 oacc[2][2];
            mfma_dense<!BF16>(a_hi, a_lo, (const __bf16*)wpack + (size_t)(9 + l) * 32768, oacc, lane, wave);
            writeC_f32(oacc, scratch, lane, wave);
        }
        __syncthreads();                                        // B6
        #pragma unroll
        for (int i = 0; i < 4; ++i) {
            float4 ov = *(const float4*)&scratch[(r0 + i) * STR + fq * 4];
            h[i][0] += ov.x; h[i][1] += ov.y; h[i][2] += ov.z; h[i][3] += ov.w;
        }

        // h += tanh(LN(h) @ Wf[l] + bf[l])
        ln_stats(h, mu, rs);
        write_a(h, mu, rs, a_hi, a_lo, r0, fq);
        __syncthreads();                                        // B7
        {
            f32x4 facc[2][2];
            mfma_dense<!BF16>(a_hi, a_lo, (const __bf16*)wpack + (size_t)(12 + l) * 32768, facc, lane, wave);
            writeC_f32(facc, scratch, lane, wave);
        }
        __syncthreads();                                        // B8
        {
            float4 bv = ld4T<BF16>(bfb, l * NF + fq * 4);
            #pragma unroll
            for (int i = 0; i < 4; ++i) {
                float z0 = scratch[(r0 + i) * STR + fq * 4 + 0] + bv.x;
                float z1 = scratch[(r0 + i) * STR + fq * 4 + 1] + bv.y;
                float z2 = scratch[(r0 + i) * STR + fq * 4 + 2] + bv.z;
                float z3 = scratch[(r0 + i) * STR + fq * 4 + 3] + bv.w;
                // tanh(z) = 1 - 2/(e^{2z}+1)
                h[i][0] += 1.f - 2.f * fast_rcp(fast_exp(2.f*z0) + 1.f);
                h[i][1] += 1.f - 2.f * fast_rcp(fast_exp(2.f*z1) + 1.f);
                h[i][2] += 1.f - 2.f * fast_rcp(fast_exp(2.f*z2) + 1.f);
                h[i][3] += 1.f - 2.f * fast_rcp(fast_exp(2.f*z3) + 1.f);
            }
        }
        // h *= mask
        #pragma unroll
        for (int i = 0; i < 4; ++i)
            if (r0 + i >= len) { h[i][0]=0.f; h[i][1]=0.f; h[i][2]=0.f; h[i][3]=0.f; }
        // next write_a is safe: all Wf a-reads finished before B8; scratch
        // readers (tanh) touch the k region, not the a region.
    }

    // out = LN(h) in output dtype (direct store, shuffle stats)
    ln_stats(h, mu, rs);
    #pragma unroll
    for (int i = 0; i < 4; ++i) {
        int idx = b * NATOM * NF + (r0 + i) * NF + fq * 4;
        float o0 = (h[i][0]-mu[i])*rs[i], o1 = (h[i][1]-mu[i])*rs[i];
        float o2 = (h[i][2]-mu[i])*rs[i], o3 = (h[i][3]-mu[i])*rs[i];
        if constexpr (BF16) {
            ushort4 o;
            o.x = bfbits(o0); o.y = bfbits(o1); o.z = bfbits(o2); o.w = bfbits(o3);
            *(ushort4*)((unsigned short*)out + idx) = o;
        } else {
            *(float4*)((float*)out + idx) = make_float4(o0, o1, o2, o3);
        }
    }
}

static constexpr size_t SMEM_BYTES =
      (size_t)NATOM * ASTRB * 2 * 2       // a_hi + a_lo
    + (size_t)NATOM * ASTRB * 2 * 2       // k_hi + k_lo (scratch overlays: 33792 <= 34816)
    + (size_t)NF * VSTR * 2 * 2           // vt_hi + vt_lo
    + (size_t)2 * NATOM * PSTR * 2 * 2    // p_hi + p_lo, per head
    + (size_t)NATOM * 4 * 4               // cs
    + 48 * 4                              // wel
    + 16;                                 // lenp (+pad)  => 144592 B

extern "C" void kernel_launch(void* const* d_in, const int* in_sizes, int n_in,
                              void* d_out, int out_size, void* d_ws, size_t ws_size,
                              hipStream_t stream) {
    const void*           coords  = d_in[0];
    const int*            species = (const int*)d_in[1];
    const unsigned char*  maskraw = (const unsigned char*)d_in[2];
    const void*           embed   = d_in[3];
    const void*           Wq      = d_in[4];
    const void*           Wk      = d_in[5];
    const void*           Wv      = d_in[6];
    const void*           Wo      = d_in[7];
    const void*           We      = d_in[8];
    const void*           Wf      = d_in[9];
    const void*           bfb     = d_in[10];

    unsigned short* wpack = (unsigned short*)d_ws;   // 15 * 32768 ushorts = 960 KB

    (void)hipFuncSetAttribute((const void*)gnn_fused<true>,
                              hipFuncAttributeMaxDynamicSharedMemorySize,
                              (int)SMEM_BYTES);
    (void)hipFuncSetAttribute((const void*)gnn_fused<false>,
                              hipFuncAttributeMaxDynamicSharedMemorySize,
                              (int)SMEM_BYTES);

    prep_w<true ><<<dim3(15), dim3(256), 0, stream>>>(Wq, Wk, Wv, Wo, Wf, wpack);
    prep_w<false><<<dim3(15), dim3(256), 0, stream>>>(Wq, Wk, Wv, Wo, Wf, wpack);

    gnn_fused<true ><<<dim3(NBATCH), dim3(NTH), SMEM_BYTES, stream>>>(
        coords, species, maskraw, embed, Wq, We, bfb, wpack, d_out);
    gnn_fused<false><<<dim3(NBATCH), dim3(NTH), SMEM_BYTES, stream>>>(
        coords, species, maskraw, embed, Wq, We, bfb, wpack, d_out);
}